// Round 5
// baseline (324.968 us; speedup 1.0000x reference)
//
#include <hip/hip_runtime.h>

#define D 64
#define SCAN_CHUNK 1024
#define NXCD 8

typedef unsigned short ushort_t;

// ---------------------------------------------------------------------------
// d_ws layout: off[int,N+1] | cur[int,N] | ssrc[int,E] | blockSums[int,256] |
//              xh[ushort, N*64]  (bf16 copy of x)
// ---------------------------------------------------------------------------

__global__ __launch_bounds__(256) void zero_kernel(int* __restrict__ p, int n) {
    int gid = blockIdx.x * 256 + threadIdx.x;
    if (gid < n) p[gid] = 0;
}

// x (fp32) -> xh (bf16, round-to-nearest-even via hardware cvt)
__global__ __launch_bounds__(256) void cast_kernel(const float4* __restrict__ x,
                                                   ushort4* __restrict__ xh,
                                                   int n4) {
    int gid = blockIdx.x * 256 + threadIdx.x;
    if (gid >= n4) return;
    float4 v = x[gid];
    ushort4 o;
    o.x = (ushort_t)(__float_as_uint(v.x) + 0x7FFF + ((__float_as_uint(v.x) >> 16) & 1)) >> 0, // placeholder, replaced below
    o.x = (ushort_t)((__float_as_uint(v.x) + 0x7FFF + ((__float_as_uint(v.x) >> 16) & 1)) >> 16);
    o.y = (ushort_t)((__float_as_uint(v.y) + 0x7FFF + ((__float_as_uint(v.y) >> 16) & 1)) >> 16);
    o.z = (ushort_t)((__float_as_uint(v.z) + 0x7FFF + ((__float_as_uint(v.z) >> 16) & 1)) >> 16);
    o.w = (ushort_t)((__float_as_uint(v.w) + 0x7FFF + ((__float_as_uint(v.w) >> 16) & 1)) >> 16);
    xh[gid] = o;
}

// ---------------------------------------------------------------------------
// XCD-partitioned histogram: block b counts only dst in XCD (b%8)'s node
// range, so each counter cache line is owned by one XCD (locality heuristic
// only; correctness independent of the blockIdx->XCD mapping).
// ---------------------------------------------------------------------------
__global__ __launch_bounds__(256) void hist_xcd_kernel(const int* __restrict__ dst,
                                                       int* __restrict__ counts,
                                                       int nEdges, int nNodes,
                                                       int blocksPerXcd) {
    int xcd = blockIdx.x % NXCD;
    int slice = blockIdx.x / NXCD;
    int lo = (int)((long long)nNodes * xcd / NXCD);
    int hi = (int)((long long)nNodes * (xcd + 1) / NXCD);
    int per = (nEdges + blocksPerXcd - 1) / blocksPerXcd;
    int e0 = slice * per;
    int e1 = min(e0 + per, nEdges);
    for (int e = e0 + (int)threadIdx.x; e < e1; e += 256) {
        int d = dst[e];
        if (d >= lo && d < hi) atomicAdd(&counts[d], 1);
    }
}

// ---- scan pass A: blockSums[b] = sum(counts[b*1024 .. b*1024+1024)) ----
__global__ __launch_bounds__(256) void scan_reduce_kernel(const int* __restrict__ counts,
                                                          int* __restrict__ blockSums,
                                                          int nNodes) {
    __shared__ int ws[4];
    int base = blockIdx.x * SCAN_CHUNK;
    int tid = threadIdx.x;
    int s = 0;
#pragma unroll
    for (int i = 0; i < 4; i++) {
        int idx = base + tid + 256 * i;
        if (idx < nNodes) s += counts[idx];
    }
#pragma unroll
    for (int d = 32; d > 0; d >>= 1) s += __shfl_xor(s, d, 64);
    if ((tid & 63) == 0) ws[tid >> 6] = s;
    __syncthreads();
    if (tid == 0) blockSums[blockIdx.x] = ws[0] + ws[1] + ws[2] + ws[3];
}

// ---- scan pass B: exclusive scan of blockSums (nSB <= 256), 1 block ----
__global__ __launch_bounds__(256) void scan_sums_kernel(int* __restrict__ blockSums,
                                                        int* __restrict__ off,
                                                        int nSB, int nNodes, int nEdges) {
    __shared__ int ws[4];
    int tid = threadIdx.x;
    int lane = tid & 63;
    int wave = tid >> 6;
    int v = (tid < nSB) ? blockSums[tid] : 0;
    int incl = v;
#pragma unroll
    for (int d = 1; d < 64; d <<= 1) {
        int t = __shfl_up(incl, d, 64);
        if (lane >= d) incl += t;
    }
    if (lane == 63) ws[wave] = incl;
    __syncthreads();
    int waveOff = 0;
#pragma unroll
    for (int w = 0; w < 4; w++)
        if (w < wave) waveOff += ws[w];
    if (tid < nSB) blockSums[tid] = waveOff + incl - v;  // exclusive
    if (tid == 0) off[nNodes] = nEdges;
}

// ---- scan pass C: rescan each chunk, add base, write off & cur ----
__global__ __launch_bounds__(1024) void scan_write_kernel(int* __restrict__ off,
                                                          int* __restrict__ cur,
                                                          const int* __restrict__ blockSums,
                                                          int nNodes) {
    __shared__ int waveSums[16];
    int tid = threadIdx.x;
    int lane = tid & 63;
    int wave = tid >> 6;
    int i = blockIdx.x * SCAN_CHUNK + tid;
    int v = (i < nNodes) ? off[i] : 0;
    int incl = v;
#pragma unroll
    for (int d = 1; d < 64; d <<= 1) {
        int t = __shfl_up(incl, d, 64);
        if (lane >= d) incl += t;
    }
    if (lane == 63) waveSums[wave] = incl;
    __syncthreads();
    if (wave == 0) {
        int wv = (lane < 16) ? waveSums[lane] : 0;
        int s = wv;
#pragma unroll
        for (int d = 1; d < 16; d <<= 1) {
            int t = __shfl_up(s, d, 64);
            if (lane >= d) s += t;
        }
        if (lane < 16) waveSums[lane] = s - wv;  // exclusive wave offsets
    }
    __syncthreads();
    if (i < nNodes) {
        int excl = blockSums[blockIdx.x] + waveSums[wave] + incl - v;
        off[i] = excl;
        cur[i] = excl;
    }
}

// ---------------------------------------------------------------------------
// XCD-partitioned fill (see hist comment).
// ---------------------------------------------------------------------------
__global__ __launch_bounds__(256) void fill_xcd_kernel(const int* __restrict__ src,
                                                       const int* __restrict__ dst,
                                                       int* __restrict__ cur,
                                                       int* __restrict__ ssrc,
                                                       int nEdges, int nNodes,
                                                       int blocksPerXcd) {
    int xcd = blockIdx.x % NXCD;
    int slice = blockIdx.x / NXCD;
    int lo = (int)((long long)nNodes * xcd / NXCD);
    int hi = (int)((long long)nNodes * (xcd + 1) / NXCD);
    int per = (nEdges + blocksPerXcd - 1) / blocksPerXcd;
    int e0 = slice * per;
    int e1 = min(e0 + per, nEdges);
    for (int e = e0 + (int)threadIdx.x; e < e1; e += 256) {
        int d = dst[e];
        if (d >= lo && d < hi) {
            int p = atomicAdd(&cur[d], 1);
            ssrc[p] = src[e];
        }
    }
}

// ---------------------------------------------------------------------------
// Aggregate (bf16 gather): out[n] = x[n] + sum_e bf16(x[ssrc[e]])
// Gather rows are 128 B (64 bf16); accumulation in fp32.
// ---------------------------------------------------------------------------
__global__ __launch_bounds__(256) void aggregate_bf16_kernel(const float* __restrict__ x,
                                                             const ushort_t* __restrict__ xh,
                                                             const int* __restrict__ off,
                                                             const int* __restrict__ ssrc,
                                                             float* __restrict__ out,
                                                             int nNodes) {
    int gid = blockIdx.x * 256 + threadIdx.x;
    int n = gid >> 4;
    if (n >= nNodes) return;
    int f = (gid & 15) * 4;
    float4 acc = *(const float4*)(x + (size_t)n * D + f);
    int e0 = off[n], e1 = off[n + 1];
    for (int e = e0; e < e1; e++) {
        int s = ssrc[e];
        ushort4 v = *(const ushort4*)(xh + (size_t)s * D + f);
        acc.x += __uint_as_float((unsigned)v.x << 16);
        acc.y += __uint_as_float((unsigned)v.y << 16);
        acc.z += __uint_as_float((unsigned)v.z << 16);
        acc.w += __uint_as_float((unsigned)v.w << 16);
    }
    *(float4*)(out + (size_t)n * D + f) = acc;
}

// fp32 fallback (used only if ws too small for xh)
__global__ __launch_bounds__(256) void aggregate_kernel(const float* __restrict__ x,
                                                        const int* __restrict__ off,
                                                        const int* __restrict__ ssrc,
                                                        float* __restrict__ out,
                                                        int nNodes) {
    int gid = blockIdx.x * 256 + threadIdx.x;
    int n = gid >> 4;
    if (n >= nNodes) return;
    int f = (gid & 15) * 4;
    float4 acc = *(const float4*)(x + (size_t)n * D + f);
    int e0 = off[n], e1 = off[n + 1];
    for (int e = e0; e < e1; e++) {
        int s = ssrc[e];
        float4 v = *(const float4*)(x + (size_t)s * D + f);
        acc.x += v.x; acc.y += v.y; acc.z += v.z; acc.w += v.w;
    }
    *(float4*)(out + (size_t)n * D + f) = acc;
}

// ---------------------------------------------------------------------------
// MLP: out[n] = relu(h[n] @ W1 + b1) @ W2 + b2 (in-place on out)
// ---------------------------------------------------------------------------
__global__ __launch_bounds__(256) void mlp_kernel(const float* hin,
                                                  const float* __restrict__ W1,
                                                  const float* __restrict__ b1,
                                                  const float* __restrict__ W2,
                                                  const float* __restrict__ b2,
                                                  float* out,
                                                  int nNodes) {
    __shared__ float sW1[D * D];
    __shared__ float sW2[D * D];
    __shared__ float sb1[D];
    __shared__ float sb2[D];

    int tid = threadIdx.x;
    const float4* w1v = (const float4*)W1;
    const float4* w2v = (const float4*)W2;
    float4* s1v = (float4*)sW1;
    float4* s2v = (float4*)sW2;
#pragma unroll
    for (int i = 0; i < 4; i++) {
        int idx = tid + 256 * i;
        s1v[idx] = w1v[idx];
        s2v[idx] = w2v[idx];
    }
    if (tid < D) {
        sb1[tid] = b1[tid];
        sb2[tid] = b2[tid];
    }
    __syncthreads();

    int node = blockIdx.x * 256 + tid;
    if (node >= nNodes) return;

    const float4* hp = (const float4*)(hin + (size_t)node * D);
    float h[D];
#pragma unroll
    for (int i = 0; i < 16; i++) {
        float4 v = hp[i];
        h[4 * i + 0] = v.x;
        h[4 * i + 1] = v.y;
        h[4 * i + 2] = v.z;
        h[4 * i + 3] = v.w;
    }

    float acc[D];
#pragma unroll
    for (int j = 0; j < D; j++) acc[j] = sb1[j];
#pragma unroll
    for (int k = 0; k < D; k++) {
        float hk = h[k];
        const float4* wr = (const float4*)(sW1 + k * D);
#pragma unroll
        for (int j = 0; j < 16; j++) {
            float4 w = wr[j];
            acc[4 * j + 0] = fmaf(hk, w.x, acc[4 * j + 0]);
            acc[4 * j + 1] = fmaf(hk, w.y, acc[4 * j + 1]);
            acc[4 * j + 2] = fmaf(hk, w.z, acc[4 * j + 2]);
            acc[4 * j + 3] = fmaf(hk, w.w, acc[4 * j + 3]);
        }
    }
#pragma unroll
    for (int j = 0; j < D; j++) h[j] = fmaxf(acc[j], 0.0f);

#pragma unroll
    for (int j = 0; j < D; j++) acc[j] = sb2[j];
#pragma unroll
    for (int k = 0; k < D; k++) {
        float hk = h[k];
        const float4* wr = (const float4*)(sW2 + k * D);
#pragma unroll
        for (int j = 0; j < 16; j++) {
            float4 w = wr[j];
            acc[4 * j + 0] = fmaf(hk, w.x, acc[4 * j + 0]);
            acc[4 * j + 1] = fmaf(hk, w.y, acc[4 * j + 1]);
            acc[4 * j + 2] = fmaf(hk, w.z, acc[4 * j + 2]);
            acc[4 * j + 3] = fmaf(hk, w.w, acc[4 * j + 3]);
        }
    }

    float4* op = (float4*)(out + (size_t)node * D);
#pragma unroll
    for (int i = 0; i < 16; i++) {
        float4 v;
        v.x = acc[4 * i + 0];
        v.y = acc[4 * i + 1];
        v.z = acc[4 * i + 2];
        v.w = acc[4 * i + 3];
        op[i] = v;
    }
}

extern "C" void kernel_launch(void* const* d_in, const int* in_sizes, int n_in,
                              void* d_out, int out_size, void* d_ws, size_t ws_size,
                              hipStream_t stream) {
    const float* x  = (const float*)d_in[0];
    const int*   ei = (const int*)d_in[1];   // [2, E] row-major, int32
    const float* W1 = (const float*)d_in[2];
    const float* b1 = (const float*)d_in[3];
    const float* W2 = (const float*)d_in[4];
    const float* b2 = (const float*)d_in[5];
    float* out = (float*)d_out;

    const int nNodes = in_sizes[0] / D;
    const int nEdges = in_sizes[1] / 2;
    const int* src = ei;
    const int* dst = ei + nEdges;

    const int nSB = (nNodes + SCAN_CHUNK - 1) / SCAN_CHUNK;  // <= 256 for N <= 256K

    int* off  = (int*)d_ws;            // N+1
    int* cur  = off + (nNodes + 1);    // N
    int* ssrc = cur + nNodes;          // E
    int* blockSums = ssrc + nEdges;    // 256
    ushort_t* xh = (ushort_t*)(blockSums + 256);   // N*64 bf16

    size_t wsNeeded = (size_t)(2 * nNodes + 1 + nEdges + 256) * 4
                    + (size_t)nNodes * D * 2;
    bool useBf16 = (ws_size >= wsNeeded);

    // 1) counts = 0  (+ bf16 cast of x, independent)
    zero_kernel<<<(nNodes + 1 + 255) / 256, 256, 0, stream>>>(off, nNodes + 1);
    if (useBf16) {
        int n4 = nNodes * (D / 4);
        cast_kernel<<<(n4 + 255) / 256, 256, 0, stream>>>((const float4*)x, (ushort4*)xh, n4);
    }
    // 2) histogram of dst, XCD-partitioned
    {
        const int blocksPerXcd = 256;
        hist_xcd_kernel<<<blocksPerXcd * NXCD, 256, 0, stream>>>(
            dst, off, nEdges, nNodes, blocksPerXcd);
    }
    // 3) multi-block exclusive scan -> off, cur
    scan_reduce_kernel<<<nSB, 256, 0, stream>>>(off, blockSums, nNodes);
    scan_sums_kernel<<<1, 256, 0, stream>>>(blockSums, off, nSB, nNodes, nEdges);
    scan_write_kernel<<<nSB, 1024, 0, stream>>>(off, cur, blockSums, nNodes);
    // 4) fill sorted src lists, XCD-partitioned by destination range
    {
        const int blocksPerXcd = 256;
        fill_xcd_kernel<<<blocksPerXcd * NXCD, 256, 0, stream>>>(
            src, dst, cur, ssrc, nEdges, nNodes, blocksPerXcd);
    }
    // 5) aggregate: out = x + segment_sum(xh[src])
    {
        long long work = (long long)nNodes * 16;
        int blocks = (int)((work + 255) / 256);
        if (useBf16)
            aggregate_bf16_kernel<<<blocks, 256, 0, stream>>>(x, xh, off, ssrc, out, nNodes);
        else
            aggregate_kernel<<<blocks, 256, 0, stream>>>(x, off, ssrc, out, nNodes);
    }
    // 6) MLP in-place
    mlp_kernel<<<(nNodes + 255) / 256, 256, 0, stream>>>(out, W1, b1, W2, b2, out, nNodes);
}

// Round 6
// 310.616 us; speedup vs baseline: 1.0462x; 1.0462x over previous
//
#include <hip/hip_runtime.h>

#define D 64
#define SCAN_CHUNK 1024
#define NXCD 8

typedef unsigned short ushort_t;

// ---------------------------------------------------------------------------
// d_ws layout: off[int,N+1] | cur[int,N] | ssrc[int,E] | blockSums[int,256] |
//              xh[ushort, N*64]  (bf16 copy of x)
// ---------------------------------------------------------------------------

__global__ __launch_bounds__(256) void zero_kernel(int* __restrict__ p, int n) {
    int gid = blockIdx.x * 256 + threadIdx.x;
    if (gid < n) p[gid] = 0;
}

// x (fp32) -> xh (bf16, round-to-nearest-even)
__global__ __launch_bounds__(256) void cast_kernel(const float4* __restrict__ x,
                                                   ushort4* __restrict__ xh,
                                                   int n4) {
    int gid = blockIdx.x * 256 + threadIdx.x;
    if (gid >= n4) return;
    float4 v = x[gid];
    ushort4 o;
    o.x = (ushort_t)((__float_as_uint(v.x) + 0x7FFF + ((__float_as_uint(v.x) >> 16) & 1)) >> 16);
    o.y = (ushort_t)((__float_as_uint(v.y) + 0x7FFF + ((__float_as_uint(v.y) >> 16) & 1)) >> 16);
    o.z = (ushort_t)((__float_as_uint(v.z) + 0x7FFF + ((__float_as_uint(v.z) >> 16) & 1)) >> 16);
    o.w = (ushort_t)((__float_as_uint(v.w) + 0x7FFF + ((__float_as_uint(v.w) >> 16) & 1)) >> 16);
    xh[gid] = o;
}

// ---------------------------------------------------------------------------
// XCD-partitioned histogram (locality heuristic only).
// ---------------------------------------------------------------------------
__global__ __launch_bounds__(256) void hist_xcd_kernel(const int* __restrict__ dst,
                                                       int* __restrict__ counts,
                                                       int nEdges, int nNodes,
                                                       int blocksPerXcd) {
    int xcd = blockIdx.x % NXCD;
    int slice = blockIdx.x / NXCD;
    int lo = (int)((long long)nNodes * xcd / NXCD);
    int hi = (int)((long long)nNodes * (xcd + 1) / NXCD);
    int per = (nEdges + blocksPerXcd - 1) / blocksPerXcd;
    int e0 = slice * per;
    int e1 = min(e0 + per, nEdges);
    for (int e = e0 + (int)threadIdx.x; e < e1; e += 256) {
        int d = dst[e];
        if (d >= lo && d < hi) atomicAdd(&counts[d], 1);
    }
}

// ---- scan pass A ----
__global__ __launch_bounds__(256) void scan_reduce_kernel(const int* __restrict__ counts,
                                                          int* __restrict__ blockSums,
                                                          int nNodes) {
    __shared__ int ws[4];
    int base = blockIdx.x * SCAN_CHUNK;
    int tid = threadIdx.x;
    int s = 0;
#pragma unroll
    for (int i = 0; i < 4; i++) {
        int idx = base + tid + 256 * i;
        if (idx < nNodes) s += counts[idx];
    }
#pragma unroll
    for (int d = 32; d > 0; d >>= 1) s += __shfl_xor(s, d, 64);
    if ((tid & 63) == 0) ws[tid >> 6] = s;
    __syncthreads();
    if (tid == 0) blockSums[blockIdx.x] = ws[0] + ws[1] + ws[2] + ws[3];
}

// ---- scan pass B ----
__global__ __launch_bounds__(256) void scan_sums_kernel(int* __restrict__ blockSums,
                                                        int* __restrict__ off,
                                                        int nSB, int nNodes, int nEdges) {
    __shared__ int ws[4];
    int tid = threadIdx.x;
    int lane = tid & 63;
    int wave = tid >> 6;
    int v = (tid < nSB) ? blockSums[tid] : 0;
    int incl = v;
#pragma unroll
    for (int d = 1; d < 64; d <<= 1) {
        int t = __shfl_up(incl, d, 64);
        if (lane >= d) incl += t;
    }
    if (lane == 63) ws[wave] = incl;
    __syncthreads();
    int waveOff = 0;
#pragma unroll
    for (int w = 0; w < 4; w++)
        if (w < wave) waveOff += ws[w];
    if (tid < nSB) blockSums[tid] = waveOff + incl - v;  // exclusive
    if (tid == 0) off[nNodes] = nEdges;
}

// ---- scan pass C ----
__global__ __launch_bounds__(1024) void scan_write_kernel(int* __restrict__ off,
                                                          int* __restrict__ cur,
                                                          const int* __restrict__ blockSums,
                                                          int nNodes) {
    __shared__ int waveSums[16];
    int tid = threadIdx.x;
    int lane = tid & 63;
    int wave = tid >> 6;
    int i = blockIdx.x * SCAN_CHUNK + tid;
    int v = (i < nNodes) ? off[i] : 0;
    int incl = v;
#pragma unroll
    for (int d = 1; d < 64; d <<= 1) {
        int t = __shfl_up(incl, d, 64);
        if (lane >= d) incl += t;
    }
    if (lane == 63) waveSums[wave] = incl;
    __syncthreads();
    if (wave == 0) {
        int wv = (lane < 16) ? waveSums[lane] : 0;
        int s = wv;
#pragma unroll
        for (int d = 1; d < 16; d <<= 1) {
            int t = __shfl_up(s, d, 64);
            if (lane >= d) s += t;
        }
        if (lane < 16) waveSums[lane] = s - wv;
    }
    __syncthreads();
    if (i < nNodes) {
        int excl = blockSums[blockIdx.x] + waveSums[wave] + incl - v;
        off[i] = excl;
        cur[i] = excl;
    }
}

// ---------------------------------------------------------------------------
// XCD-partitioned fill (locality heuristic only).
// ---------------------------------------------------------------------------
__global__ __launch_bounds__(256) void fill_xcd_kernel(const int* __restrict__ src,
                                                       const int* __restrict__ dst,
                                                       int* __restrict__ cur,
                                                       int* __restrict__ ssrc,
                                                       int nEdges, int nNodes,
                                                       int blocksPerXcd) {
    int xcd = blockIdx.x % NXCD;
    int slice = blockIdx.x / NXCD;
    int lo = (int)((long long)nNodes * xcd / NXCD);
    int hi = (int)((long long)nNodes * (xcd + 1) / NXCD);
    int per = (nEdges + blocksPerXcd - 1) / blocksPerXcd;
    int e0 = slice * per;
    int e1 = min(e0 + per, nEdges);
    for (int e = e0 + (int)threadIdx.x; e < e1; e += 256) {
        int d = dst[e];
        if (d >= lo && d < hi) {
            int p = atomicAdd(&cur[d], 1);
            ssrc[p] = src[e];
        }
    }
}

// ---------------------------------------------------------------------------
// Aggregate (bf16 gather): out[n] = x[n] + sum_e bf16(x[ssrc[e]])
// ---------------------------------------------------------------------------
__global__ __launch_bounds__(256) void aggregate_bf16_kernel(const float* __restrict__ x,
                                                             const ushort_t* __restrict__ xh,
                                                             const int* __restrict__ off,
                                                             const int* __restrict__ ssrc,
                                                             float* __restrict__ out,
                                                             int nNodes) {
    int gid = blockIdx.x * 256 + threadIdx.x;
    int n = gid >> 4;
    if (n >= nNodes) return;
    int f = (gid & 15) * 4;
    float4 acc = *(const float4*)(x + (size_t)n * D + f);
    int e0 = off[n], e1 = off[n + 1];
    for (int e = e0; e < e1; e++) {
        int s = ssrc[e];
        ushort4 v = *(const ushort4*)(xh + (size_t)s * D + f);
        acc.x += __uint_as_float((unsigned)v.x << 16);
        acc.y += __uint_as_float((unsigned)v.y << 16);
        acc.z += __uint_as_float((unsigned)v.z << 16);
        acc.w += __uint_as_float((unsigned)v.w << 16);
    }
    *(float4*)(out + (size_t)n * D + f) = acc;
}

// fp32 fallback (used only if ws too small for xh)
__global__ __launch_bounds__(256) void aggregate_kernel(const float* __restrict__ x,
                                                        const int* __restrict__ off,
                                                        const int* __restrict__ ssrc,
                                                        float* __restrict__ out,
                                                        int nNodes) {
    int gid = blockIdx.x * 256 + threadIdx.x;
    int n = gid >> 4;
    if (n >= nNodes) return;
    int f = (gid & 15) * 4;
    float4 acc = *(const float4*)(x + (size_t)n * D + f);
    int e0 = off[n], e1 = off[n + 1];
    for (int e = e0; e < e1; e++) {
        int s = ssrc[e];
        float4 v = *(const float4*)(x + (size_t)s * D + f);
        acc.x += v.x; acc.y += v.y; acc.z += v.z; acc.w += v.w;
    }
    *(float4*)(out + (size_t)n * D + f) = acc;
}

// ---------------------------------------------------------------------------
// Weight-stationary MLP: one WAVE per node, lane j owns output feature j.
// Both weight columns live in VGPRs (w1[64], w2[64] = 128 VGPR); h[k] is
// broadcast via v_readlane (SGPR) -- no LDS, no ds_read in the hot loop.
// 4 partial accumulators break the FMA dependency chain.
// In-place safe: each wave fully reads its node row before writing it.
// ---------------------------------------------------------------------------
__global__ __launch_bounds__(256) void mlp_reg_kernel(const float* hin,
                                                      const float* __restrict__ W1,
                                                      const float* __restrict__ b1,
                                                      const float* __restrict__ W2,
                                                      const float* __restrict__ b2,
                                                      float* out,
                                                      int nNodes) {
    int lane = threadIdx.x & 63;
    int wave = threadIdx.x >> 6;

    // Weight columns into registers: w1[k] = W1[k][lane] (coalesced per k).
    float w1[D], w2[D];
#pragma unroll
    for (int k = 0; k < D; k++) w1[k] = W1[k * D + lane];
#pragma unroll
    for (int k = 0; k < D; k++) w2[k] = W2[k * D + lane];
    float bb1 = b1[lane];
    float bb2 = b2[lane];

    int gw = blockIdx.x * 4 + wave;   // global wave id
    int nW = gridDim.x * 4;
    for (int n = gw; n < nNodes; n += nW) {
        float hv = hin[(size_t)n * D + lane];
        float a0 = bb1, a1 = 0.0f, a2 = 0.0f, a3 = 0.0f;
#pragma unroll
        for (int k = 0; k < D; k += 4) {
            float h0 = __uint_as_float(__builtin_amdgcn_readlane(__float_as_uint(hv), k + 0));
            float h1 = __uint_as_float(__builtin_amdgcn_readlane(__float_as_uint(hv), k + 1));
            float h2 = __uint_as_float(__builtin_amdgcn_readlane(__float_as_uint(hv), k + 2));
            float h3 = __uint_as_float(__builtin_amdgcn_readlane(__float_as_uint(hv), k + 3));
            a0 = fmaf(h0, w1[k + 0], a0);
            a1 = fmaf(h1, w1[k + 1], a1);
            a2 = fmaf(h2, w1[k + 2], a2);
            a3 = fmaf(h3, w1[k + 3], a3);
        }
        float m = fmaxf((a0 + a1) + (a2 + a3), 0.0f);
        float c0 = bb2, c1 = 0.0f, c2 = 0.0f, c3 = 0.0f;
#pragma unroll
        for (int k = 0; k < D; k += 4) {
            float h0 = __uint_as_float(__builtin_amdgcn_readlane(__float_as_uint(m), k + 0));
            float h1 = __uint_as_float(__builtin_amdgcn_readlane(__float_as_uint(m), k + 1));
            float h2 = __uint_as_float(__builtin_amdgcn_readlane(__float_as_uint(m), k + 2));
            float h3 = __uint_as_float(__builtin_amdgcn_readlane(__float_as_uint(m), k + 3));
            c0 = fmaf(h0, w2[k + 0], c0);
            c1 = fmaf(h1, w2[k + 1], c1);
            c2 = fmaf(h2, w2[k + 2], c2);
            c3 = fmaf(h3, w2[k + 3], c3);
        }
        out[(size_t)n * D + lane] = (c0 + c1) + (c2 + c3);
    }
}

extern "C" void kernel_launch(void* const* d_in, const int* in_sizes, int n_in,
                              void* d_out, int out_size, void* d_ws, size_t ws_size,
                              hipStream_t stream) {
    const float* x  = (const float*)d_in[0];
    const int*   ei = (const int*)d_in[1];   // [2, E] row-major, int32
    const float* W1 = (const float*)d_in[2];
    const float* b1 = (const float*)d_in[3];
    const float* W2 = (const float*)d_in[4];
    const float* b2 = (const float*)d_in[5];
    float* out = (float*)d_out;

    const int nNodes = in_sizes[0] / D;
    const int nEdges = in_sizes[1] / 2;
    const int* src = ei;
    const int* dst = ei + nEdges;

    const int nSB = (nNodes + SCAN_CHUNK - 1) / SCAN_CHUNK;

    int* off  = (int*)d_ws;            // N+1
    int* cur  = off + (nNodes + 1);    // N
    int* ssrc = cur + nNodes;          // E
    int* blockSums = ssrc + nEdges;    // 256
    ushort_t* xh = (ushort_t*)(blockSums + 256);   // N*64 bf16

    size_t wsNeeded = (size_t)(2 * nNodes + 1 + nEdges + 256) * 4
                    + (size_t)nNodes * D * 2;
    bool useBf16 = (ws_size >= wsNeeded);

    // 1) counts = 0  (+ bf16 cast of x, independent)
    zero_kernel<<<(nNodes + 1 + 255) / 256, 256, 0, stream>>>(off, nNodes + 1);
    if (useBf16) {
        int n4 = nNodes * (D / 4);
        cast_kernel<<<(n4 + 255) / 256, 256, 0, stream>>>((const float4*)x, (ushort4*)xh, n4);
    }
    // 2) histogram of dst, XCD-partitioned
    {
        const int blocksPerXcd = 256;
        hist_xcd_kernel<<<blocksPerXcd * NXCD, 256, 0, stream>>>(
            dst, off, nEdges, nNodes, blocksPerXcd);
    }
    // 3) multi-block exclusive scan -> off, cur
    scan_reduce_kernel<<<nSB, 256, 0, stream>>>(off, blockSums, nNodes);
    scan_sums_kernel<<<1, 256, 0, stream>>>(blockSums, off, nSB, nNodes, nEdges);
    scan_write_kernel<<<nSB, 1024, 0, stream>>>(off, cur, blockSums, nNodes);
    // 4) fill sorted src lists, XCD-partitioned by destination range
    {
        const int blocksPerXcd = 256;
        fill_xcd_kernel<<<blocksPerXcd * NXCD, 256, 0, stream>>>(
            src, dst, cur, ssrc, nEdges, nNodes, blocksPerXcd);
    }
    // 5) aggregate: out = x + segment_sum(xh[src])
    {
        long long work = (long long)nNodes * 16;
        int blocks = (int)((work + 255) / 256);
        if (useBf16)
            aggregate_bf16_kernel<<<blocks, 256, 0, stream>>>(x, xh, off, ssrc, out, nNodes);
        else
            aggregate_kernel<<<blocks, 256, 0, stream>>>(x, off, ssrc, out, nNodes);
    }
    // 6) MLP in-place: one wave per node, weights in VGPRs
    {
        int blocks = 6250;   // 25000 waves, 4 nodes/wave grid-stride
        mlp_reg_kernel<<<blocks, 256, 0, stream>>>(out, W1, b1, W2, b2, out, nNodes);
    }
}

// Round 7
// 280.082 us; speedup vs baseline: 1.1603x; 1.1090x over previous
//
#include <hip/hip_runtime.h>

#define D 64
#define SCAN_CHUNK 1024
#define NXCD 8

typedef unsigned short ushort_t;
typedef __bf16 bf16_t;
typedef __bf16 bf16x8 __attribute__((ext_vector_type(8)));
typedef float f32x4 __attribute__((ext_vector_type(4)));

__device__ __forceinline__ ushort_t f2bf(float v) {
    unsigned u = __float_as_uint(v);
    return (ushort_t)((u + 0x7FFF + ((u >> 16) & 1)) >> 16);
}
__device__ __forceinline__ float bf2f(ushort_t h) {
    return __uint_as_float((unsigned)h << 16);
}

// ---------------------------------------------------------------------------
// d_ws layout (tier A):
//   off[int,N+1] | cur[int,N] | ssrc[int,E] | blockSums[int,256] |
//   xh[ushort,N*64] | hb[ushort,N*64] | w1t[ushort,4096] | w2t[ushort,4096]
// ---------------------------------------------------------------------------

__global__ __launch_bounds__(256) void zero_kernel(int* __restrict__ p, int n) {
    int gid = blockIdx.x * 256 + threadIdx.x;
    if (gid < n) p[gid] = 0;
}

// x (fp32) -> xh (bf16 RNE)
__global__ __launch_bounds__(256) void cast_kernel(const float4* __restrict__ x,
                                                   ushort4* __restrict__ xh,
                                                   int n4) {
    int gid = blockIdx.x * 256 + threadIdx.x;
    if (gid >= n4) return;
    float4 v = x[gid];
    ushort4 o;
    o.x = f2bf(v.x); o.y = f2bf(v.y); o.z = f2bf(v.z); o.w = f2bf(v.w);
    xh[gid] = o;
}

// W[k*64+n] (fp32) -> wT[n*64+k] (bf16): B-fragments become contiguous.
// block 0 -> W1, block 1 -> W2.
__global__ __launch_bounds__(256) void cast_wT_kernel(const float* __restrict__ W1,
                                                      const float* __restrict__ W2,
                                                      ushort_t* __restrict__ w1t,
                                                      ushort_t* __restrict__ w2t) {
    const float* W = (blockIdx.x == 0) ? W1 : W2;
    ushort_t* T = (blockIdx.x == 0) ? w1t : w2t;
    for (int i = 0; i < 16; i++) {
        int idx = i * 256 + threadIdx.x;   // 4096 elements
        int k = idx >> 6, n = idx & 63;
        T[n * 64 + k] = f2bf(W[idx]);
    }
}

// ---------------------------------------------------------------------------
// XCD-partitioned histogram (locality heuristic only).
// ---------------------------------------------------------------------------
__global__ __launch_bounds__(256) void hist_xcd_kernel(const int* __restrict__ dst,
                                                       int* __restrict__ counts,
                                                       int nEdges, int nNodes,
                                                       int blocksPerXcd) {
    int xcd = blockIdx.x % NXCD;
    int slice = blockIdx.x / NXCD;
    int lo = (int)((long long)nNodes * xcd / NXCD);
    int hi = (int)((long long)nNodes * (xcd + 1) / NXCD);
    int per = (nEdges + blocksPerXcd - 1) / blocksPerXcd;
    int e0 = slice * per;
    int e1 = min(e0 + per, nEdges);
    for (int e = e0 + (int)threadIdx.x; e < e1; e += 256) {
        int d = dst[e];
        if (d >= lo && d < hi) atomicAdd(&counts[d], 1);
    }
}

// ---- scan pass A ----
__global__ __launch_bounds__(256) void scan_reduce_kernel(const int* __restrict__ counts,
                                                          int* __restrict__ blockSums,
                                                          int nNodes) {
    __shared__ int ws[4];
    int base = blockIdx.x * SCAN_CHUNK;
    int tid = threadIdx.x;
    int s = 0;
#pragma unroll
    for (int i = 0; i < 4; i++) {
        int idx = base + tid + 256 * i;
        if (idx < nNodes) s += counts[idx];
    }
#pragma unroll
    for (int d = 32; d > 0; d >>= 1) s += __shfl_xor(s, d, 64);
    if ((tid & 63) == 0) ws[tid >> 6] = s;
    __syncthreads();
    if (tid == 0) blockSums[blockIdx.x] = ws[0] + ws[1] + ws[2] + ws[3];
}

// ---- scan pass B ----
__global__ __launch_bounds__(256) void scan_sums_kernel(int* __restrict__ blockSums,
                                                        int* __restrict__ off,
                                                        int nSB, int nNodes, int nEdges) {
    __shared__ int ws[4];
    int tid = threadIdx.x;
    int lane = tid & 63;
    int wave = tid >> 6;
    int v = (tid < nSB) ? blockSums[tid] : 0;
    int incl = v;
#pragma unroll
    for (int d = 1; d < 64; d <<= 1) {
        int t = __shfl_up(incl, d, 64);
        if (lane >= d) incl += t;
    }
    if (lane == 63) ws[wave] = incl;
    __syncthreads();
    int waveOff = 0;
#pragma unroll
    for (int w = 0; w < 4; w++)
        if (w < wave) waveOff += ws[w];
    if (tid < nSB) blockSums[tid] = waveOff + incl - v;  // exclusive
    if (tid == 0) off[nNodes] = nEdges;
}

// ---- scan pass C ----
__global__ __launch_bounds__(1024) void scan_write_kernel(int* __restrict__ off,
                                                          int* __restrict__ cur,
                                                          const int* __restrict__ blockSums,
                                                          int nNodes) {
    __shared__ int waveSums[16];
    int tid = threadIdx.x;
    int lane = tid & 63;
    int wave = tid >> 6;
    int i = blockIdx.x * SCAN_CHUNK + tid;
    int v = (i < nNodes) ? off[i] : 0;
    int incl = v;
#pragma unroll
    for (int d = 1; d < 64; d <<= 1) {
        int t = __shfl_up(incl, d, 64);
        if (lane >= d) incl += t;
    }
    if (lane == 63) waveSums[wave] = incl;
    __syncthreads();
    if (wave == 0) {
        int wv = (lane < 16) ? waveSums[lane] : 0;
        int s = wv;
#pragma unroll
        for (int d = 1; d < 16; d <<= 1) {
            int t = __shfl_up(s, d, 64);
            if (lane >= d) s += t;
        }
        if (lane < 16) waveSums[lane] = s - wv;
    }
    __syncthreads();
    if (i < nNodes) {
        int excl = blockSums[blockIdx.x] + waveSums[wave] + incl - v;
        off[i] = excl;
        cur[i] = excl;
    }
}

// ---------------------------------------------------------------------------
// XCD-partitioned fill (locality heuristic only).
// ---------------------------------------------------------------------------
__global__ __launch_bounds__(256) void fill_xcd_kernel(const int* __restrict__ src,
                                                       const int* __restrict__ dst,
                                                       int* __restrict__ cur,
                                                       int* __restrict__ ssrc,
                                                       int nEdges, int nNodes,
                                                       int blocksPerXcd) {
    int xcd = blockIdx.x % NXCD;
    int slice = blockIdx.x / NXCD;
    int lo = (int)((long long)nNodes * xcd / NXCD);
    int hi = (int)((long long)nNodes * (xcd + 1) / NXCD);
    int per = (nEdges + blocksPerXcd - 1) / blocksPerXcd;
    int e0 = slice * per;
    int e1 = min(e0 + per, nEdges);
    for (int e = e0 + (int)threadIdx.x; e < e1; e += 256) {
        int d = dst[e];
        if (d >= lo && d < hi) {
            int p = atomicAdd(&cur[d], 1);
            ssrc[p] = src[e];
        }
    }
}

// ---------------------------------------------------------------------------
// Aggregate -> bf16 h: hb[n] = bf16( xh[n] + sum_e xh[ssrc[e]] )
// 16 threads per node, fp32 register accumulation.
// ---------------------------------------------------------------------------
__global__ __launch_bounds__(256) void aggregate_h_kernel(const ushort_t* __restrict__ xh,
                                                          const int* __restrict__ off,
                                                          const int* __restrict__ ssrc,
                                                          ushort_t* __restrict__ hb,
                                                          int nNodes) {
    int gid = blockIdx.x * 256 + threadIdx.x;
    int n = gid >> 4;
    if (n >= nNodes) return;
    int f = (gid & 15) * 4;
    ushort4 sv = *(const ushort4*)(xh + (size_t)n * D + f);
    float4 acc;
    acc.x = bf2f(sv.x); acc.y = bf2f(sv.y); acc.z = bf2f(sv.z); acc.w = bf2f(sv.w);
    int e0 = off[n], e1 = off[n + 1];
    for (int e = e0; e < e1; e++) {
        int s = ssrc[e];
        ushort4 v = *(const ushort4*)(xh + (size_t)s * D + f);
        acc.x += bf2f(v.x); acc.y += bf2f(v.y); acc.z += bf2f(v.z); acc.w += bf2f(v.w);
    }
    ushort4 o;
    o.x = f2bf(acc.x); o.y = f2bf(acc.y); o.z = f2bf(acc.z); o.w = f2bf(acc.w);
    *(ushort4*)(hb + (size_t)n * D + f) = o;
}

// fp32 fallback aggregate (tier B/C)
__global__ __launch_bounds__(256) void aggregate_kernel(const float* __restrict__ x,
                                                        const int* __restrict__ off,
                                                        const int* __restrict__ ssrc,
                                                        float* __restrict__ out,
                                                        int nNodes) {
    int gid = blockIdx.x * 256 + threadIdx.x;
    int n = gid >> 4;
    if (n >= nNodes) return;
    int f = (gid & 15) * 4;
    float4 acc = *(const float4*)(x + (size_t)n * D + f);
    int e0 = off[n], e1 = off[n + 1];
    for (int e = e0; e < e1; e++) {
        int s = ssrc[e];
        float4 v = *(const float4*)(x + (size_t)s * D + f);
        acc.x += v.x; acc.y += v.y; acc.z += v.z; acc.w += v.w;
    }
    *(float4*)(out + (size_t)n * D + f) = acc;
}

// ---------------------------------------------------------------------------
// MFMA MLP: one wave per 16-node tile.
//   layer1: D1 = relu(A(16x64) . W1(64x64) + b1); layer2: out = D1 . W2 + b2
// A-frag (mfma_f32_16x16x32_bf16):  A[m=lane&15][k=(lane>>4)*8 + j]
// B-frag:                           B[k=(lane>>4)*8 + j][n=lane&15]  (wT rows)
// C/D:                              row=(lane>>4)*4+r, col=lane&15
// Layer1->layer2 relayout via per-wave LDS (stride 72 ushorts, 16B-aligned).
// ---------------------------------------------------------------------------
#define HSTR 72
__global__ __launch_bounds__(256) void mlp_mfma_kernel(const ushort_t* __restrict__ hb,
                                                       const ushort_t* __restrict__ w1t,
                                                       const ushort_t* __restrict__ w2t,
                                                       const float* __restrict__ b1,
                                                       const float* __restrict__ b2,
                                                       float* __restrict__ out,
                                                       int nNodes, int nTiles) {
    __shared__ ushort_t sh[4][16 * HSTR];
    int lane = threadIdx.x & 63;
    int wave = threadIdx.x >> 6;
    int quad = lane >> 4;
    int col = lane & 15;

    // B fragments: contiguous 16B loads from transposed bf16 weights.
    bf16x8 w1f[4][2], w2f[4][2];
#pragma unroll
    for (int nt = 0; nt < 4; nt++)
#pragma unroll
        for (int ks = 0; ks < 2; ks++) {
            int n = nt * 16 + col;
            w1f[nt][ks] = *(const bf16x8*)(w1t + n * 64 + ks * 32 + quad * 8);
            w2f[nt][ks] = *(const bf16x8*)(w2t + n * 64 + ks * 32 + quad * 8);
        }
    float bb1[4], bb2[4];
#pragma unroll
    for (int nt = 0; nt < 4; nt++) {
        bb1[nt] = b1[nt * 16 + col];
        bb2[nt] = b2[nt * 16 + col];
    }

    ushort_t* sw = sh[wave];
    int gw = blockIdx.x * 4 + wave;
    int nW = gridDim.x * 4;
    for (int tile = gw; tile < nTiles; tile += nW) {
        int base = tile * 16;
        // layer-1 A frags: 16B contiguous per lane
        int arow = min(base + col, nNodes - 1);
        const ushort_t* hp = hb + (size_t)arow * D;
        bf16x8 a0 = *(const bf16x8*)(hp + quad * 8);
        bf16x8 a1 = *(const bf16x8*)(hp + 32 + quad * 8);

        // layer 1 MFMAs, then bias+relu, stage to LDS as bf16
        f32x4 c;
#pragma unroll
        for (int nt = 0; nt < 4; nt++) {
            c = (f32x4){0.f, 0.f, 0.f, 0.f};
            c = __builtin_amdgcn_mfma_f32_16x16x32_bf16(a0, w1f[nt][0], c, 0, 0, 0);
            c = __builtin_amdgcn_mfma_f32_16x16x32_bf16(a1, w1f[nt][1], c, 0, 0, 0);
#pragma unroll
            for (int r = 0; r < 4; r++) {
                float v = fmaxf(c[r] + bb1[nt], 0.0f);
                int m = quad * 4 + r;
                sw[m * HSTR + nt * 16 + col] = f2bf(v);
            }
        }
        // layer-2 A frags from LDS (same-wave RAW; compiler inserts lgkmcnt)
        bf16x8 d0 = *(const bf16x8*)(sw + col * HSTR + quad * 8);
        bf16x8 d1 = *(const bf16x8*)(sw + col * HSTR + 32 + quad * 8);
#pragma unroll
        for (int nt = 0; nt < 4; nt++) {
            c = (f32x4){0.f, 0.f, 0.f, 0.f};
            c = __builtin_amdgcn_mfma_f32_16x16x32_bf16(d0, w2f[nt][0], c, 0, 0, 0);
            c = __builtin_amdgcn_mfma_f32_16x16x32_bf16(d1, w2f[nt][1], c, 0, 0, 0);
#pragma unroll
            for (int r = 0; r < 4; r++) {
                int row = base + quad * 4 + r;
                if (row < nNodes) out[(size_t)row * D + nt * 16 + col] = c[r] + bb2[nt];
            }
        }
    }
}

// ---------------------------------------------------------------------------
// Fallback vector-ALU MLP (tier B/C): one wave per node, weights in VGPRs.
// ---------------------------------------------------------------------------
__global__ __launch_bounds__(256) void mlp_reg_kernel(const float* hin,
                                                      const float* __restrict__ W1,
                                                      const float* __restrict__ b1,
                                                      const float* __restrict__ W2,
                                                      const float* __restrict__ b2,
                                                      float* out,
                                                      int nNodes) {
    int lane = threadIdx.x & 63;
    int wave = threadIdx.x >> 6;
    float w1[D], w2[D];
#pragma unroll
    for (int k = 0; k < D; k++) w1[k] = W1[k * D + lane];
#pragma unroll
    for (int k = 0; k < D; k++) w2[k] = W2[k * D + lane];
    float bb1 = b1[lane];
    float bb2 = b2[lane];
    int gw = blockIdx.x * 4 + wave;
    int nW = gridDim.x * 4;
    for (int n = gw; n < nNodes; n += nW) {
        float hv = hin[(size_t)n * D + lane];
        float a0 = bb1, a1 = 0.0f, a2 = 0.0f, a3 = 0.0f;
#pragma unroll
        for (int k = 0; k < D; k += 4) {
            float h0 = __uint_as_float(__builtin_amdgcn_readlane(__float_as_uint(hv), k + 0));
            float h1 = __uint_as_float(__builtin_amdgcn_readlane(__float_as_uint(hv), k + 1));
            float h2 = __uint_as_float(__builtin_amdgcn_readlane(__float_as_uint(hv), k + 2));
            float h3 = __uint_as_float(__builtin_amdgcn_readlane(__float_as_uint(hv), k + 3));
            a0 = fmaf(h0, w1[k + 0], a0);
            a1 = fmaf(h1, w1[k + 1], a1);
            a2 = fmaf(h2, w1[k + 2], a2);
            a3 = fmaf(h3, w1[k + 3], a3);
        }
        float m = fmaxf((a0 + a1) + (a2 + a3), 0.0f);
        float c0 = bb2, c1 = 0.0f, c2 = 0.0f, c3 = 0.0f;
#pragma unroll
        for (int k = 0; k < D; k += 4) {
            float h0 = __uint_as_float(__builtin_amdgcn_readlane(__float_as_uint(m), k + 0));
            float h1 = __uint_as_float(__builtin_amdgcn_readlane(__float_as_uint(m), k + 1));
            float h2 = __uint_as_float(__builtin_amdgcn_readlane(__float_as_uint(m), k + 2));
            float h3 = __uint_as_float(__builtin_amdgcn_readlane(__float_as_uint(m), k + 3));
            c0 = fmaf(h0, w2[k + 0], c0);
            c1 = fmaf(h1, w2[k + 1], c1);
            c2 = fmaf(h2, w2[k + 2], c2);
            c3 = fmaf(h3, w2[k + 3], c3);
        }
        out[(size_t)n * D + lane] = (c0 + c1) + (c2 + c3);
    }
}

extern "C" void kernel_launch(void* const* d_in, const int* in_sizes, int n_in,
                              void* d_out, int out_size, void* d_ws, size_t ws_size,
                              hipStream_t stream) {
    const float* x  = (const float*)d_in[0];
    const int*   ei = (const int*)d_in[1];   // [2, E] row-major, int32
    const float* W1 = (const float*)d_in[2];
    const float* b1 = (const float*)d_in[3];
    const float* W2 = (const float*)d_in[4];
    const float* b2 = (const float*)d_in[5];
    float* out = (float*)d_out;

    const int nNodes = in_sizes[0] / D;
    const int nEdges = in_sizes[1] / 2;
    const int* src = ei;
    const int* dst = ei + nEdges;

    const int nSB = (nNodes + SCAN_CHUNK - 1) / SCAN_CHUNK;

    int* off  = (int*)d_ws;            // N+1
    int* cur  = off + (nNodes + 1);    // N
    int* ssrc = cur + nNodes;          // E
    int* blockSums = ssrc + nEdges;    // 256
    ushort_t* xh  = (ushort_t*)(blockSums + 256);   // N*64
    ushort_t* hb  = xh + (size_t)nNodes * D;        // N*64
    ushort_t* w1t = hb + (size_t)nNodes * D;        // 4096
    ushort_t* w2t = w1t + 4096;                     // 4096

    size_t wsBase = (size_t)(2 * nNodes + 1 + nEdges + 256) * 4;
    size_t wsA = wsBase + (size_t)nNodes * D * 2 * 2 + 2 * 4096 * 2;
    size_t wsB = wsBase + (size_t)nNodes * D * 2;
    int tier = (ws_size >= wsA) ? 0 : (ws_size >= wsB ? 1 : 2);

    // CSR build (all tiers)
    zero_kernel<<<(nNodes + 1 + 255) / 256, 256, 0, stream>>>(off, nNodes + 1);
    if (tier <= 1) {
        int n4 = nNodes * (D / 4);
        cast_kernel<<<(n4 + 255) / 256, 256, 0, stream>>>((const float4*)x, (ushort4*)xh, n4);
    }
    if (tier == 0) cast_wT_kernel<<<2, 256, 0, stream>>>(W1, W2, w1t, w2t);
    {
        const int blocksPerXcd = 256;
        hist_xcd_kernel<<<blocksPerXcd * NXCD, 256, 0, stream>>>(
            dst, off, nEdges, nNodes, blocksPerXcd);
    }
    scan_reduce_kernel<<<nSB, 256, 0, stream>>>(off, blockSums, nNodes);
    scan_sums_kernel<<<1, 256, 0, stream>>>(blockSums, off, nSB, nNodes, nEdges);
    scan_write_kernel<<<nSB, 1024, 0, stream>>>(off, cur, blockSums, nNodes);
    {
        const int blocksPerXcd = 256;
        fill_xcd_kernel<<<blocksPerXcd * NXCD, 256, 0, stream>>>(
            src, dst, cur, ssrc, nEdges, nNodes, blocksPerXcd);
    }

    long long work = (long long)nNodes * 16;
    int aggBlocks = (int)((work + 255) / 256);
    if (tier == 0) {
        // bf16 aggregate into hb, then MFMA MLP -> out
        aggregate_h_kernel<<<aggBlocks, 256, 0, stream>>>(xh, off, ssrc, hb, nNodes);
        int nTiles = (nNodes + 15) / 16;
        int blocks = (nTiles + 3) / 4;
        mlp_mfma_kernel<<<blocks, 256, 0, stream>>>(hb, w1t, w2t, b1, b2, out, nNodes, nTiles);
    } else {
        // fallback: fp32 aggregate into out, vector-ALU MLP in-place
        aggregate_kernel<<<aggBlocks, 256, 0, stream>>>(x, off, ssrc, out, nNodes);
        mlp_reg_kernel<<<6250, 256, 0, stream>>>(out, W1, b1, W2, b2, out, nNodes);
    }
}